// Round 4
// baseline (4863.609 us; speedup 1.0000x reference)
//
#include <hip/hip_runtime.h>
#include <hip/hip_fp16.h>
#include <stdint.h>

// Gated LSTM: B=64, T=2048, I=128, H=256, O=1.
// Persistent kernel: 64 WGs = 8 batch-groups x 8 N-slices.
// Each WG: 256 threads, batches g*8..g*8+7, h-outputs j = p*32..p*32+31.
// W slice lives in VGPRs as f16 MFMA B-fragments (zero per-step W traffic).
//
// R6: once-per-step data read + cheap flag hint (kills the RMW-sweep storm).
//  * R4/R5 established: exchange must be TCC-point atomics (sc0 loads do NOT
//    bypass L1 on gfx950 -- two independent probe failures), and R4's cost
//    was the SWEEP: 1792 RMWs/WG repeated per polling round.
//  * New protocol: packed slots {tag32|h16|h16} (128/WG, parity-buffered),
//    per-WG monotone flag (own line) as a readiness HINT (7 RMWs/wave gate),
//    speculative first data round (steady state: one 896-RMW round total).
//    Data tags still gate everything -> no ordering assumptions, no probe,
//    no fallback ladder. All primitives are R4-proven workgroup-scope RMWs.
//  * x-part MFMAs (kt 0-3) moved BEFORE the poll: gx(t+1) is staged during
//    step t into parity-buffered XLDS, so 8/24 MFMAs run off the critical
//    path. Barriers stay at 2 per step.
//  * Placement-derived grouping kept (XCC_ID handshake, R4-proven). If the
//    table is unbalanced: default grouping + agent-scope RMWs (correct
//    cross-XCD, R2 speed).

#define NB 64
#define NT 2048
#define NI 128
#define NH 256

typedef _Float16 h8_t __attribute__((ext_vector_type(8)));
typedef _Float16 h4_t __attribute__((ext_vector_type(4)));
typedef float f4_t __attribute__((ext_vector_type(4)));

__device__ __forceinline__ float sigm(float x) {
  return __builtin_amdgcn_rcpf(1.f + __expf(-x));
}
__device__ __forceinline__ float tanh_f(float x) {
  return 1.f - 2.f * __builtin_amdgcn_rcpf(1.f + __expf(2.f * x));
}

// ws layout (u64 index):
//   [0,16384)      data slots [parity2][g8][ps8][bl8][jj16] {tag32|h16|h16}
//   [16384,16896)  flags, one per (g,ps), stride 8 (own 64B line each)
//   [16896,16960)  xcc table (64), tagged (gen<<8)|xcc
//   [16960,17024)  generation slots (64)
// Slots are role-indexed: stale cross-dispatch values are benign (gen-salted
// tags; identical inputs => identical values anyway).

#define DATARND(DB, TG32, S) do {                                           \
  uint64_t v[7];                                                            \
  _Pragma("unroll")                                                         \
  for (int s7 = 0; s7 < 7; ++s7)                                            \
    if (need & (1u << s7))                                                  \
      v[s7] = __hip_atomic_fetch_or((DB) + didx[s7], z0,                    \
                                    __ATOMIC_RELAXED, S);                   \
  _Pragma("unroll")                                                         \
  for (int s7 = 0; s7 < 7; ++s7)                                            \
    if ((need & (1u << s7)) && (unsigned)(v[s7] >> 32) == (TG32)) {         \
      int ps = (s7 < p) ? s7 : s7 + 1;                                      \
      *(unsigned*)(&HLDS[bl][ps * 32 + 2 * jj]) = (unsigned)v[s7];          \
      need &= ~(1u << s7);                                                  \
    }                                                                       \
} while (0)

#define STEP(T, XVC, WGC, XVN, WGN, S) do {                                 \
  const int tt = (T);                                                       \
  if (tt + 2 < NT) {   /* prefetch x(t+2) into the buffer x(t) vacated */   \
    XVC = *(const f4_t*)(xd + xbase + (size_t)(tt + 2) * NI);               \
    WGC = *(const f4_t*)(w  + xbase + (size_t)(tt + 2) * NI);               \
  }                                                                         \
  /* ---- early MFMA: x-part (kt 0-3), staged last step, no poll dep ---- */\
  f4_t acc0 = {0.f, 0.f, 0.f, 0.f}, acc1 = {0.f, 0.f, 0.f, 0.f};           \
  {                                                                         \
    const _Float16* xb = &XLDS[tt & 1][0][0];                               \
    _Pragma("unroll")                                                       \
    for (int kt = 0; kt < 4; ++kt) {                                        \
      h8_t af = *(const h8_t*)(xb + cc * 136 + kt * 32 + q * 8);            \
      acc0 = __builtin_amdgcn_mfma_f32_16x16x32_f16(af, wf[0][kt], acc0,    \
                                                    0, 0, 0);               \
      acc1 = __builtin_amdgcn_mfma_f32_16x16x32_f16(af, wf[1][kt], acc1,    \
                                                    0, 0, 0);               \
    }                                                                       \
  }                                                                         \
  /* ---- poll partners' h(t): hint gate + once-ish data read ---- */       \
  if (tt > 0) {                                                             \
    const uint64_t tgt = (gen << 12) | (uint64_t)tt;                        \
    const unsigned tg32 = (unsigned)tgt;                                    \
    uint64_t* db = DAT + ((tt & 1) << 13);                                  \
    unsigned need = (jj < 16) ? 0x7fu : 0u;                                 \
    if (need) DATARND(db, tg32, S);    /* speculative: steady-state hit */  \
    if (__ballot(need != 0)) {                                              \
      for (;;) {                       /* cheap flag gate: 7 RMW / wave */  \
        uint64_t fv = 0;                                                    \
        if (lane < 7)                                                       \
          fv = __hip_atomic_fetch_or(FLG + fidx_l, z0,                      \
                                     __ATOMIC_RELAXED, S);                  \
        if (__ballot((lane < 7) ? (fv >= tgt) : 1) == ~0ull) break;         \
      }                                                                     \
      while (need) DATARND(db, tg32, S);                                    \
    }                                                                       \
  }                                                                         \
  __syncthreads();                       /* barrier 1: A-tile complete */   \
  /* ---- stage gx(t+1) into XLDS[(t+1)&1] (no partner dependency) ---- */  \
  if (tt + 1 < NT) {                                                        \
    h4_t gx;                                                                \
    gx[0] = (_Float16)(XVN[0] * sigm(WGN[0]));                              \
    gx[1] = (_Float16)(XVN[1] * sigm(WGN[1]));                              \
    gx[2] = (_Float16)(XVN[2] * sigm(WGN[2]));                              \
    gx[3] = (_Float16)(XVN[3] * sigm(WGN[3]));                              \
    *(h4_t*)(&XLDS[(tt + 1) & 1][bl][jj * 4]) = gx;                         \
  }                                                                         \
  /* ---- late MFMA: h-part (kt 4-11) ---- */                               \
  _Pragma("unroll")                                                         \
  for (int kt = 4; kt < 12; ++kt) {                                         \
    h8_t af = *(const h8_t*)(&HLDS[cc][(kt - 4) * 32 + q * 8]);             \
    acc0 = __builtin_amdgcn_mfma_f32_16x16x32_f16(af, wf[0][kt], acc0,      \
                                                  0, 0, 0);                 \
    acc1 = __builtin_amdgcn_mfma_f32_16x16x32_f16(af, wf[1][kt], acc1,      \
                                                  0, 0, 0);                 \
  }                                                                         \
  if (q < 2) {                                                              \
    _Pragma("unroll")                                                       \
    for (int r = 0; r < 4; ++r) {                                           \
      Zlds[16 * (2 * wv)     + cc][q * 4 + r] = acc0[r];                    \
      Zlds[16 * (2 * wv + 1) + cc][q * 4 + r] = acc1[r];                    \
    }                                                                       \
  }                                                                         \
  __syncthreads();                       /* barrier 2: Z complete */        \
  /* ---- epilogue: gates, state, packed publish + flag ---- */             \
  {                                                                         \
    float zi = Zlds[jj * 4 + 0][bl] + bias[0];                              \
    float zf = Zlds[jj * 4 + 1][bl] + bias[1];                              \
    float zg = Zlds[jj * 4 + 2][bl] + bias[2];                              \
    float zo = Zlds[jj * 4 + 3][bl] + bias[3];                              \
    creg = sigm(zf) * creg + sigm(zi) * tanh_f(zg);                         \
    hreg = sigm(zo) * tanh_f(creg);                                         \
    HLDS[bl][p * 32 + jj] = (_Float16)hreg;   /* own slice for t+1 */       \
    float h0 = __shfl(hreg, slA, 64);          /* convergent shfls */       \
    float h1 = __shfl(hreg, slA + 1, 64);                                   \
    if (jj < 16) {                                                          \
      _Float16 a0 = (_Float16)h0, a1 = (_Float16)h1;                        \
      unsigned h01 = (unsigned)*(unsigned short*)&a0 |                      \
                     ((unsigned)*(unsigned short*)&a1 << 16);               \
      unsigned tagp = (unsigned)((gen << 12) | (uint64_t)(tt + 1));         \
      uint64_t pay = ((uint64_t)tagp << 32) | h01;                          \
      (void)__hip_atomic_exchange(DAT + (((tt + 1) & 1) << 13) + dmy, pay,  \
                                  __ATOMIC_RELAXED, S);                     \
    }                                                                       \
    if (tid == 0)                                                           \
      (void)__hip_atomic_exchange(FLG + fown,                               \
                                  (gen << 12) | (uint64_t)(tt + 1),         \
                                  __ATOMIC_RELAXED, S);                     \
  }                                                                         \
} while (0)

__launch_bounds__(256, 1)
__global__ void lstm_persist(
    const float* __restrict__ xd, const float* __restrict__ w,
    const float* __restrict__ W_ih, const float* __restrict__ b_ih,
    const float* __restrict__ W_hh, const float* __restrict__ b_hh,
    const float* __restrict__ W_out, const float* __restrict__ b_out,
    float* __restrict__ out, uint64_t* ex, int mode)
{
  const int bid = blockIdx.x;
  const int tid = threadIdx.x;
  const int lane = tid & 63;
  const int wv = tid >> 6;      // wave 0..3
  const int q  = lane >> 4;     // 0..3
  const int cc = lane & 15;
  const int bl = tid >> 5;      // 0..7
  const int jj = tid & 31;      // 0..31

  // A-tile x-part, parity-buffered (staged one step ahead); +8 f16 pad
  __shared__ _Float16 XLDS[2][16][136];
  // A-tile h-part (single buffer; writes/reads barrier-separated); +8 pad
  __shared__ _Float16 HLDS[16][264];
  __shared__ float Zlds[128][17];
  __shared__ int xcc_sh[64];
  __shared__ int meta_sh[3];    // bal, g, p
  __shared__ uint64_t gen_sh;

  for (int i = tid; i < 2 * 16 * 136; i += 256) (&XLDS[0][0][0])[i] = (_Float16)0.f;
  for (int i = tid; i < 16 * 264;     i += 256) (&HLDS[0][0])[i]    = (_Float16)0.f;

  // opaque zero: compiler can't fold fetch_or(slot, z0) into a plain load
  uint64_t z0;
  asm volatile("s_mov_b64 %0, 0" : "=s"(z0));

  uint64_t* const DAT = ex;
  uint64_t* const FLG = ex + 16384;
  uint64_t* const XCC = ex + 16896;
  uint64_t* const GEN = ex + 16960;

  int g, p, bal = 0;
  uint64_t gen = 1;

  if (mode) {
    // generation: uniform across WGs (identical per-slot histories)
    if (tid == 0) {
      uint64_t old = __hip_atomic_fetch_add(GEN + bid, 1, __ATOMIC_RELAXED,
                                            __HIP_MEMORY_SCOPE_AGENT);
      gen_sh = (old + 1) & 0x00FFFFFFFFFFFFFFull;
    }
    __syncthreads();
    gen = gen_sh;

    // publish my physical XCC, gather the full table (full 64-WG rendezvous)
    if (tid == 0) {
      unsigned x;
      asm volatile("s_getreg_b32 %0, hwreg(HW_REG_XCC_ID)" : "=s"(x));
      __hip_atomic_store(XCC + bid, (gen << 8) | (uint64_t)(x & 0xffu),
                         __ATOMIC_RELAXED, __HIP_MEMORY_SCOPE_AGENT);
    }
    if (tid < 64) {
      uint64_t e;
      do {
        e = __hip_atomic_load(XCC + tid, __ATOMIC_RELAXED,
                              __HIP_MEMORY_SCOPE_AGENT);
      } while ((e >> 8) != gen);
      xcc_sh[tid] = (int)(e & 0xff);
    }
    __syncthreads();

    // derive grouping from placement; bal = exactly 8 WGs per distinct XCC
    if (tid == 0) {
      const int myx = xcc_sh[bid];
      int balL = 1;
      for (int b = 0; b < 64; ++b) {
        int c = 0;
        for (int b2 = 0; b2 < 64; ++b2) c += (xcc_sh[b2] == xcc_sh[b]);
        if (c != 8) { balL = 0; break; }
      }
      int gd = 0, rank = 0;
      for (int b = 0; b < 64; ++b) {
        if (xcc_sh[b] == myx) {
          if (b < bid) rank++;
        } else if (xcc_sh[b] < myx) {
          bool first = true;
          for (int b2 = 0; b2 < b; ++b2)
            if (xcc_sh[b2] == xcc_sh[b]) { first = false; break; }
          gd += first;
        }
      }
      meta_sh[0] = balL; meta_sh[1] = gd; meta_sh[2] = rank;
    }
    __syncthreads();
    bal = meta_sh[0];
    if (bal) { g = meta_sh[1]; p = meta_sh[2]; }
    else     { g = bid & 7;    p = bid >> 3;   }
  } else {
    g = bid & 7;
    p = bid >> 3;
  }

  // ---- W B-fragments, resident in registers (uses derived p) ----
  h8_t wf[2][12];
  for (int nt = 0; nt < 2; ++nt) {
    int r = 16 * (2 * wv + nt) + cc;
    int R = (r & 3) * NH + p * 32 + (r >> 2);
    for (int kt = 0; kt < 12; ++kt) {
      int k = kt * 32 + q * 8;
      const float* s = (k < NI) ? (W_ih + (size_t)R * NI + k)
                                : (W_hh + (size_t)R * NH + (k - NI));
      f4_t lo = *(const f4_t*)s;
      f4_t hi = *(const f4_t*)(s + 4);
      h8_t hh;
      hh[0] = (_Float16)lo[0]; hh[1] = (_Float16)lo[1];
      hh[2] = (_Float16)lo[2]; hh[3] = (_Float16)lo[3];
      hh[4] = (_Float16)hi[0]; hh[5] = (_Float16)hi[1];
      hh[6] = (_Float16)hi[2]; hh[7] = (_Float16)hi[3];
      wf[nt][kt] = hh;
    }
  }

  float bias[4];
  #pragma unroll
  for (int gate = 0; gate < 4; ++gate)
    bias[gate] = b_ih[gate * NH + p * 32 + jj] + b_hh[gate * NH + p * 32 + jj];

  // ---- exchange addressing ----
  int didx[7];
  #pragma unroll
  for (int s7 = 0; s7 < 7; ++s7) {
    int ps = (s7 < p) ? s7 : s7 + 1;
    didx[s7] = (g * 8 + ps) * 128 + bl * 16 + jj;   // valid for jj<16 readers
  }
  const int s7l = (lane < 7) ? lane : 0;
  const int psl = (s7l < p) ? s7l : s7l + 1;
  const int fidx_l = (g * 8 + psl) * 8;
  const int fown = (g * 8 + p) * 8;
  const int dmy = (g * 8 + p) * 128 + bl * 16 + jj; // packer slot (jj<16)
  const int slA = (bl & 1) * 32 + 2 * jj;           // shfl src (jj<16)

  float creg = 0.f;
  float hreg = 0.f;
  const size_t xbase = ((size_t)(g * 8 + bl) * NT) * NI + jj * 4;

  // prologue: stage gx(0) directly; preload x(1) into the B buffers
  f4_t xvA = *(const f4_t*)(xd + xbase);
  f4_t wgA = *(const f4_t*)(w  + xbase);
  {
    h4_t gx;
    gx[0] = (_Float16)(xvA[0] * sigm(wgA[0]));
    gx[1] = (_Float16)(xvA[1] * sigm(wgA[1]));
    gx[2] = (_Float16)(xvA[2] * sigm(wgA[2]));
    gx[3] = (_Float16)(xvA[3] * sigm(wgA[3]));
    *(h4_t*)(&XLDS[0][bl][jj * 4]) = gx;
  }
  f4_t xvB = *(const f4_t*)(xd + xbase + NI);
  f4_t wgB = *(const f4_t*)(w  + xbase + NI);

  __syncthreads();   // XLDS/HLDS zeros + gx(0) staged before first step

  if (bal) {
    for (int t = 0; t < NT; t += 2) {
      STEP(t,     xvA, wgA, xvB, wgB, __HIP_MEMORY_SCOPE_WORKGROUP);
      STEP(t + 1, xvB, wgB, xvA, wgA, __HIP_MEMORY_SCOPE_WORKGROUP);
    }
  } else {
    for (int t = 0; t < NT; t += 2) {
      STEP(t,     xvA, wgA, xvB, wgB, __HIP_MEMORY_SCOPE_AGENT);
      STEP(t + 1, xvB, wgB, xvA, wgA, __HIP_MEMORY_SCOPE_AGENT);
    }
  }

  // ---- output: out[b] = h_T . W_out + b_out, by p==0 WGs ----
  // h(NT) carries tag (gen<<12)|NT in parity 0; own slice already in HLDS.
  if (p == 0) {
    const uint64_t tgt = (gen << 12) | (uint64_t)NT;
    const unsigned tg32 = (unsigned)tgt;
    uint64_t* db = DAT;                     // parity NT&1 == 0
    unsigned need = (jj < 16) ? 0x7fu : 0u;
    if (need) DATARND(db, tg32,
                      bal ? __HIP_MEMORY_SCOPE_WORKGROUP
                          : __HIP_MEMORY_SCOPE_AGENT);
    if (__ballot(need != 0)) {
      for (;;) {
        uint64_t fv = 0;
        if (lane < 7)
          fv = __hip_atomic_fetch_or(FLG + fidx_l, z0, __ATOMIC_RELAXED,
                                     bal ? __HIP_MEMORY_SCOPE_WORKGROUP
                                         : __HIP_MEMORY_SCOPE_AGENT);
        if (__ballot((lane < 7) ? (fv >= tgt) : 1) == ~0ull) break;
      }
      while (need) DATARND(db, tg32,
                           bal ? __HIP_MEMORY_SCOPE_WORKGROUP
                               : __HIP_MEMORY_SCOPE_AGENT);
    }
    __syncthreads();                        // HLDS h(NT) complete
    float sum = 0.f;
    #pragma unroll
    for (int s = 0; s < 8; ++s)
      sum += (float)HLDS[bl][s * 32 + jj] * W_out[s * 32 + jj];
    #pragma unroll
    for (int m = 16; m >= 1; m >>= 1) sum += __shfl_xor(sum, m, 64);
    if (jj == 0) out[g * 8 + bl] = sum + b_out[0];
  }
}

extern "C" void kernel_launch(void* const* d_in, const int* in_sizes, int n_in,
                              void* d_out, int out_size, void* d_ws, size_t ws_size,
                              hipStream_t stream) {
  (void)in_sizes; (void)n_in; (void)out_size;
  const float* xd    = (const float*)d_in[0];
  const float* w     = (const float*)d_in[1];
  const float* W_ih  = (const float*)d_in[2];
  const float* b_ih  = (const float*)d_in[3];
  const float* W_hh  = (const float*)d_in[4];
  const float* b_hh  = (const float*)d_in[5];
  const float* W_out = (const float*)d_in[6];
  const float* b_out = (const float*)d_in[7];
  uint64_t* ex = (uint64_t*)d_ws;
  // ws: data 128KB + flags 4KB + xcc/gen 1KB = 136,192 B. If smaller, skip
  // the handshake: default grouping + agent scope (correct on any placement).
  const size_t NEEDED = (size_t)17024 * 8;
  int mode = (ws_size >= NEEDED) ? 1 : 0;
  lstm_persist<<<dim3(64), dim3(256), 0, stream>>>(
      xd, w, W_ih, b_ih, W_hh, b_hh, W_out, b_out, (float*)d_out, ex, mode);
}